// Round 5
// baseline (1411.446 us; speedup 1.0000x reference)
//
#include <hip/hip_runtime.h>
#include <hip/hip_bf16.h>

using bf16 = __hip_bfloat16;
typedef __attribute__((ext_vector_type(8))) short short8;   // 8 bf16 = 4 VGPRs
typedef __attribute__((ext_vector_type(4))) float f32x4;    // MFMA C/D frag

#define MFMA_BF16(A,B,C) __builtin_amdgcn_mfma_f32_16x16x32_bf16((A),(B),(C),0,0,0)

static __device__ __forceinline__ unsigned bf16bits(float f) {
  union { bf16 h; unsigned short u; } cv; cv.h = __float2bfloat16(f); return cv.u;
}

// agent-scope (LLC-coherent) 16B h-fragment load as 2x8B relaxed atomics
static __device__ __forceinline__ short8 ldh16(const bf16* p) {
  const unsigned long long* q = (const unsigned long long*)p;
  unsigned long long lo = __hip_atomic_load(q,     __ATOMIC_RELAXED, __HIP_MEMORY_SCOPE_AGENT);
  unsigned long long hi = __hip_atomic_load(q + 1, __ATOMIC_RELAXED, __HIP_MEMORY_SCOPE_AGENT);
  union { unsigned long long u[2]; short8 v; } cv;
  cv.u[0] = lo; cv.u[1] = hi;
  return cv.v;
}

// async global->LDS, 16B per lane. LDS dest = wave-uniform base + lane*16.
static __device__ __forceinline__ void gload16(const void* g, void* l) {
  __builtin_amdgcn_global_load_lds(
      (const __attribute__((address_space(1))) void*)g,
      (__attribute__((address_space(3))) void*)l, 16, 0, 0);
}

// ---------------------------------------------------------------------------
// Generic bf16 GEMM: C[M,N] = A[M,K] @ B[N,K]^T (+bias)
// m97 structure: 128x128 tile, BK=32, 4 waves (2x2), 4x4 16x16x32 frags/wave.
// EPI 0: fp32 out, ld=Nreal.  EPI 1: tanh(x*BN_SCALE) -> bf16.
// EPI 2: g0p write — B is the ROW-PERMUTED Wih0 (n -> orig g*1024+b*4+hc),
//        output scattered to [b][t][r][q] (q=g*4+hc) for coalesced gate reads.
// ---------------------------------------------------------------------------
template<int EPI>
__global__ __launch_bounds__(256)
void gemm_bt(const bf16* __restrict__ A, const bf16* __restrict__ B,
             const float* __restrict__ bias1, const float* __restrict__ bias2,
             float* __restrict__ Cf, bf16* __restrict__ Cb,
             int M, int N, int K, int Nreal)
{
  __shared__ __align__(1024) bf16 As[128*32];
  __shared__ __align__(1024) bf16 Bs[128*32];
  const int tid  = threadIdx.x;
  const int wave = tid >> 6, lane = tid & 63;
  const int wr = wave >> 1, wc = wave & 1;
  const int row0 = blockIdx.y * 128;
  const int col0 = blockIdx.x * 128;

  f32x4 acc[4][4];
  #pragma unroll
  for (int m = 0; m < 4; ++m)
    #pragma unroll
    for (int n = 0; n < 4; ++n) { f32x4 z = {0.f,0.f,0.f,0.f}; acc[m][n] = z; }

  const int r_sub = lane >> 2;   // 0..15 (row within 16-row stage group)
  const int kc    = lane & 3;    // 16B chunk within 64B row

  for (int k0 = 0; k0 < K; k0 += 32) {
    __syncthreads();
    #pragma unroll
    for (int j = 0; j < 2; ++j) {
      const int rb = wave*32 + j*16;
      gload16(A + (size_t)(row0 + rb + r_sub)*K + k0 + kc*8,
              (void*)((char*)As + (size_t)rb*64));
      gload16(B + (size_t)(col0 + rb + r_sub)*K + k0 + kc*8,
              (void*)((char*)Bs + (size_t)rb*64));
    }
    __syncthreads();

    short8 af[4], bfv[4];
    #pragma unroll
    for (int m = 0; m < 4; ++m)
      af[m] = *(const short8*)(As + (wr*64 + m*16 + (lane&15))*32 + (lane>>4)*8);
    #pragma unroll
    for (int n = 0; n < 4; ++n)
      bfv[n] = *(const short8*)(Bs + (wc*64 + n*16 + (lane&15))*32 + (lane>>4)*8);
    #pragma unroll
    for (int m = 0; m < 4; ++m)
      #pragma unroll
      for (int n = 0; n < 4; ++n)
        acc[m][n] = MFMA_BF16(af[m], bfv[n], acc[m][n]);
  }

  const float BN_SCALE = 0.9999950000374997f;  // 1/sqrt(1+1e-5)
  #pragma unroll
  for (int m = 0; m < 4; ++m) {
    const int rg0 = row0 + wr*64 + m*16 + ((lane>>4)<<2);
    #pragma unroll
    for (int n = 0; n < 4; ++n) {
      const int cg = col0 + wc*64 + n*16 + (lane&15);
      if (EPI == 2) {
        const int bq = cg >> 4, q = cg & 15;
        const int orig = (q>>2)*1024 + bq*4 + (q&3);   // permuted -> original col
        const float bb = bias1[orig] + bias2[orig];
        #pragma unroll
        for (int j = 0; j < 4; ++j) {
          const int row = rg0 + j;
          Cf[((size_t)bq*64 + (row>>5))*512 + (size_t)(row&31)*16 + q]
              = acc[m][n][j] + bb;
        }
      } else if (cg < Nreal) {
        float bb = 0.f;
        if (bias1) bb += bias1[cg];
        if (bias2) bb += bias2[cg];
        #pragma unroll
        for (int j = 0; j < 4; ++j) {
          float v = acc[m][n][j] + bb;
          if (EPI == 1) {
            v = tanhf(v * BN_SCALE);
            Cb[(size_t)(rg0+j)*Nreal + cg] = __float2bfloat16(v);
          } else {
            Cf[(size_t)(rg0+j)*Nreal + cg] = v;
          }
        }
      }
    }
  }
}

// ---------------------------------------------------------------------------
// Persistent LSTM recurrence. 256 blocks x 256 threads, 1 block/CU.
// ALL cross-block traffic (h, flags) uses agent-scope RELAXED atomics (sc1,
// LLC-coherent, bypasses the non-coherent per-XCD L2). NO acquire fence in
// the loop -> Wpack/g0p stay L2-warm for all 65 steps. Barrier = flag array:
// block b stores flag[b]=s+1 after __syncthreads (which drains its h-stores);
// every wave polls all 256 flags in parallel (4/lane) - zero atomic RMWs.
// Each (address,value) is written once and read only after its flag is seen,
// so relaxed ordering suffices (no ABA, no stale-line reuse).
// ---------------------------------------------------------------------------
__global__ __launch_bounds__(256, 1)
void k_lstm_persist(const bf16* __restrict__ hinit, const float* __restrict__ cx,
                    const bf16* __restrict__ Wpack, const float* __restrict__ g0p,
                    const float* __restrict__ bih1, const float* __restrict__ bhh1,
                    bf16* __restrict__ h0_all, bf16* __restrict__ h1_all,
                    float* __restrict__ tail, unsigned* __restrict__ flags)
{
  const int b    = blockIdx.x;
  const int tid  = threadIdx.x;
  const int wave = tid >> 6, lane = tid & 63;

  __shared__ float P[4][2][32][20];    // padded: <=2-way on write/read

  // gate/cell phase mapping: one LSTM cell per thread
  const int layer = tid >> 7;
  const int cell  = tid & 127;
  const int r     = cell >> 2;
  const int hc    = cell & 3;
  const int col   = b*4 + hc;
  float creg = cx[(size_t)layer*32768 + (size_t)r*1024 + col];
  float bsum[4];
  #pragma unroll
  for (int g = 0; g < 4; ++g)
    bsum[g] = (layer == 1) ? (bih1[g*1024 + col] + bhh1[g*1024 + col]) : 0.f;

  const bf16* wbase = Wpack + (size_t)b * 96 * 64 * 8;
  const int arow = lane & 15;
  const int koff = (lane >> 4) * 8;

  for (int s = 0; s < 65; ++s) {
    const bf16* hA = (s == 0) ? hinit           : h0_all + (size_t)(s-1)*32768;
    const bf16* hB = (s <= 1) ? (hinit + 32768) : h1_all + (size_t)(s-2)*32768;

    // issue ALL h loads up front (LLC-coherent atomics, batched in flight)
    short8 a0[8], a1[8], c0[8], c1[8];
    #pragma unroll
    for (int i = 0; i < 8; ++i) {
      const int kb = (wave*8 + i) * 32;
      a0[i] = ldh16(hA + (size_t)arow*1024      + kb + koff);
      a1[i] = ldh16(hA + (size_t)(arow+16)*1024 + kb + koff);
      c0[i] = ldh16(hB + (size_t)arow*1024      + kb + koff);
      c1[i] = ldh16(hB + (size_t)(arow+16)*1024 + kb + koff);
    }
    // this step's g0p slice + weights: normal cached loads (L2-warm)
    float gpre[4] = {0.f, 0.f, 0.f, 0.f};
    if (layer == 0 && s < 64) {
      const float* gr = g0p + ((size_t)(b*64 + s)*32 + r)*16;
      #pragma unroll
      for (int g = 0; g < 4; ++g) gpre[g] = gr[g*4 + hc];
    }

    f32x4 z = {0.f,0.f,0.f,0.f};
    f32x4 acc00 = z, acc01 = z, acc10 = z, acc11 = z;
    #pragma unroll
    for (int i = 0; i < 8; ++i) {
      short8 w0 = *(const short8*)(wbase + ((size_t)(     wave*8+i)*64 + lane)*8);
      short8 w1 = *(const short8*)(wbase + ((size_t)(32 + wave*8+i)*64 + lane)*8);
      short8 w2 = *(const short8*)(wbase + ((size_t)(64 + wave*8+i)*64 + lane)*8);
      acc00 = MFMA_BF16(a0[i], w0, acc00);   // layer0: Whh0 @ h0[s-1]
      acc01 = MFMA_BF16(a1[i], w0, acc01);
      acc10 = MFMA_BF16(a0[i], w1, acc10);   // layer1: Wih1 @ h0[s-1]
      acc11 = MFMA_BF16(a1[i], w1, acc11);
      acc10 = MFMA_BF16(c0[i], w2, acc10);   // layer1 += Whh1 @ h1[s-2]
      acc11 = MFMA_BF16(c1[i], w2, acc11);
    }

    #pragma unroll
    for (int j = 0; j < 4; ++j) {
      const int pr = (lane >> 4)*4 + j;
      P[wave][0][pr     ][lane & 15] = acc00[j];
      P[wave][0][pr + 16][lane & 15] = acc01[j];
      P[wave][1][pr     ][lane & 15] = acc10[j];
      P[wave][1][pr + 16][lane & 15] = acc11[j];
    }
    __syncthreads();

    const int t = s - layer;
    if (t >= 0 && t < 64) {
      float v[4];
      #pragma unroll
      for (int g = 0; g < 4; ++g) {
        const int j = g*4 + hc;
        v[g] = P[0][layer][r][j] + P[1][layer][r][j]
             + P[2][layer][r][j] + P[3][layer][r][j] + bsum[g] + gpre[g];
      }
      const float iv = 1.f/(1.f + expf(-v[0]));
      const float fv = 1.f/(1.f + expf(-v[1]));
      const float gv = tanhf(v[2]);
      const float ov = 1.f/(1.f + expf(-v[3]));
      creg = fv*creg + iv*gv;
      const float hn = ov*tanhf(creg);
      // gather 4 cells -> one 8B agent-relaxed store (cols b*4..b*4+3)
      unsigned hu  = bf16bits(hn);
      unsigned p01 = hu | ((unsigned)__shfl_xor((int)hu, 1) << 16);
      unsigned p23 = (unsigned)__shfl_xor((int)p01, 2);
      if (hc == 0) {
        bf16* hp = (layer ? h1_all : h0_all) + (size_t)t*32768 + (size_t)r*1024 + b*4;
        unsigned long long v64 = (unsigned long long)p01
                               | ((unsigned long long)p23 << 32);
        __hip_atomic_store((unsigned long long*)hp, v64,
                           __ATOMIC_RELAXED, __HIP_MEMORY_SCOPE_AGENT);
      }
      if (t == 63) {
        tail[(size_t)layer*32768 + (size_t)r*1024 + col]         = hn;
        tail[65536 + (size_t)layer*32768 + (size_t)r*1024 + col] = creg;
      }
    }
    if (s == 64) break;                 // last step: no publish/wait needed

    __syncthreads();                    // drains h-stores (vmcnt 0) block-wide
    if (tid == 0)
      __hip_atomic_store(flags + b, (unsigned)(s + 1),
                         __ATOMIC_RELEASE, __HIP_MEMORY_SCOPE_AGENT);
    // every wave polls all 256 flags (4 per lane), relaxed, parallel
    {
      const unsigned su = (unsigned)s;
      const int f0 = lane * 4;
      for (;;) {
        unsigned v0 = __hip_atomic_load(flags + f0 + 0, __ATOMIC_RELAXED, __HIP_MEMORY_SCOPE_AGENT);
        unsigned v1 = __hip_atomic_load(flags + f0 + 1, __ATOMIC_RELAXED, __HIP_MEMORY_SCOPE_AGENT);
        unsigned v2 = __hip_atomic_load(flags + f0 + 2, __ATOMIC_RELAXED, __HIP_MEMORY_SCOPE_AGENT);
        unsigned v3 = __hip_atomic_load(flags + f0 + 3, __ATOMIC_RELAXED, __HIP_MEMORY_SCOPE_AGENT);
        bool ok = (v0 > su) & (v1 > su) & (v2 > su) & (v3 > su);
        if (__all(ok)) break;
        __builtin_amdgcn_s_sleep(1);
      }
    }
    // no trailing __syncthreads: P-writes are wave-private; cross-wave P
    // ordering is protected by the mid-step __syncthreads.
  }
}

// ---------------------------------------------------------------------------
// Pack Whh0 / Wih1 / Whh1 into per-block MFMA-fragment order (bf16).
// ---------------------------------------------------------------------------
__global__ __launch_bounds__(256)
void k_pack(const float* __restrict__ Whh0, const float* __restrict__ Wih1,
            const float* __restrict__ Whh1, bf16* __restrict__ Wpack)
{
  const int b = blockIdx.x;
  #pragma unroll 4
  for (int it = 0; it < 24; ++it) {
    const int idx = it*256 + threadIdx.x;
    const int chunkp = idx >> 6;            // 0..95
    const int l = idx & 63;
    const int p = chunkp >> 5, c = chunkp & 31;
    const float* W = (p == 0) ? Whh0 : (p == 1 ? Wih1 : Whh1);
    const int j = l & 15;
    const int row = (j>>2)*1024 + b*4 + (j&3);
    const int k = c*32 + (l>>4)*8;
    const float* src = W + (size_t)row*1024 + k;
    bf16* dst = Wpack + ((size_t)(b*96 + chunkp)*64 + l)*8;
    #pragma unroll
    for (int q = 0; q < 8; ++q) dst[q] = __float2bfloat16(src[q]);
  }
}

// ---------------------------------------------------------------------------
// small helpers
// ---------------------------------------------------------------------------
__global__ void k_cvt(const float* __restrict__ s, bf16* __restrict__ d, long n) {
  long i = (long)blockIdx.x*blockDim.x + threadIdx.x;
  if (i < n) d[i] = __float2bfloat16(s[i]);
}

// Wih0 cast with ROW PERMUTATION: dst row n <- src row ((n>>2)&3)*1024 + (n>>4)*4 + (n&3)
__global__ void k_cvt_perm(const float* __restrict__ src, bf16* __restrict__ dst) {
  const int n = blockIdx.x;                 // 0..4095 (permuted row)
  const int orig = ((n>>2)&3)*1024 + (n>>4)*4 + (n&3);
  const float4 v = ((const float4*)(src + (size_t)orig*512))[threadIdx.x];
  bf16* d = dst + (size_t)n*512 + threadIdx.x*4;
  d[0] = __float2bfloat16(v.x); d[1] = __float2bfloat16(v.y);
  d[2] = __float2bfloat16(v.z); d[3] = __float2bfloat16(v.w);
}

__global__ void k_cvt_pad(const float* __restrict__ s, bf16* __restrict__ d,
                          long n, long nrows_real, int rowlen) {
  long i = (long)blockIdx.x*blockDim.x + threadIdx.x;
  if (i < n) {
    long r = i / rowlen;
    d[i] = (r < nrows_real) ? __float2bfloat16(s[i]) : __float2bfloat16(0.f);
  }
}

__global__ void k_init(const float* __restrict__ hx, bf16* __restrict__ hinit,
                       unsigned* __restrict__ bar) {
  int i = blockIdx.x*blockDim.x + threadIdx.x;
  if (i < 256) bar[i] = 0u;
  if (i < 65536) hinit[i] = __float2bfloat16(hx[i]);
}

__global__ void k_embed(const int* __restrict__ ids, const float* __restrict__ emb_w,
                        bf16* __restrict__ out) {
  const int row = blockIdx.x;
  const int tok = ids[row];
  const float4 v = ((const float4*)(emb_w + (size_t)tok*512))[threadIdx.x];
  bf16* d = out + (size_t)row*512 + threadIdx.x*4;
  d[0] = __float2bfloat16(v.x); d[1] = __float2bfloat16(v.y);
  d[2] = __float2bfloat16(v.z); d[3] = __float2bfloat16(v.w);
}

// ---------------------------------------------------------------------------
extern "C" void kernel_launch(void* const* d_in, const int* in_sizes, int n_in,
                              void* d_out, int out_size, void* d_ws, size_t ws_size,
                              hipStream_t stream) {
  const int*   ids  = (const int*)d_in[0];
  const float* hx   = (const float*)d_in[1];
  const float* cx   = (const float*)d_in[2];
  const float* embw = (const float*)d_in[3];
  const float* Wih0 = (const float*)d_in[4];
  const float* Whh0 = (const float*)d_in[5];
  const float* bih0 = (const float*)d_in[6];
  const float* bhh0 = (const float*)d_in[7];
  const float* Wih1 = (const float*)d_in[8];
  const float* Whh1 = (const float*)d_in[9];
  const float* bih1 = (const float*)d_in[10];
  const float* bhh1 = (const float*)d_in[11];
  const float* Wp   = (const float*)d_in[12];
  const float* bp   = (const float*)d_in[13];
  const float* Wd   = (const float*)d_in[14];
  const float* bd   = (const float*)d_in[15];
  float* out = (float*)d_out;

  char* w = (char*)d_ws;
  bf16* Wih0b = (bf16*)w; w += 4096l*512*2;       // permuted rows
  bf16* Wpack = (bf16*)w; w += 256l*96*64*8*2;    // 24 MB packed recurrent weights
  bf16* Wpb   = (bf16*)w; w += 512l*1024*2;
  bf16* Wdb   = (bf16*)w; w += 50048l*512*2;
  bf16* embb  = (bf16*)w; w += 2048l*512*2;
  float* g0p  = (float*)w; w += 2048l*4096*4;     // [b][t][r][q] layout
  bf16* h0a   = (bf16*)w; w += 2048l*1024*2;
  bf16* h1a   = (bf16*)w; w += 2048l*1024*2;
  bf16* hinit = (bf16*)w; w += 2l*32*1024*2;
  bf16* pb    = (bf16*)w; w += 2048l*512*2;
  unsigned* flags = (unsigned*)w; w += 1024;

  k_cvt_perm<<<4096, 128, 0, stream>>>(Wih0, Wih0b);
  k_cvt<<<(512l*1024 + 255)/256, 256, 0, stream>>>(Wp, Wpb, 512l*1024);
  k_cvt_pad<<<(50048l*512 + 255)/256, 256, 0, stream>>>(Wd, Wdb, 50048l*512, 50000, 512);
  k_init<<<256, 256, 0, stream>>>(hx, hinit, flags);
  k_embed<<<2048, 128, 0, stream>>>(ids, embw, embb);
  k_pack<<<256, 256, 0, stream>>>(Whh0, Wih1, Whh1, Wpack);

  // layer-0 input-side GEMM for ALL timesteps -> g0p layout; folds bih0+bhh0
  gemm_bt<2><<<dim3(32, 16), 256, 0, stream>>>(
      embb, Wih0b, bih0, bhh0, g0p, nullptr, 2048, 4096, 512, 4096);

  // persistent pipelined recurrence: one dispatch, 65 super-steps
  float* tail = out + 102400000l;
  k_lstm_persist<<<256, 256, 0, stream>>>(hinit, cx, Wpack, g0p, bih1, bhh1,
                                          h0a, h1a, tail, flags);

  // predictor: Linear + BN(eval) + tanh -> bf16
  gemm_bt<1><<<dim3(4, 16), 256, 0, stream>>>(
      h1a, Wpb, bp, nullptr, nullptr, pb, 2048, 512, 1024, 512);

  // decoder: [2048,512] @ [50048,512]^T (padded), guarded store to 50000
  gemm_bt<0><<<dim3(391, 16), 256, 0, stream>>>(
      pb, Wdb, bd, nullptr, out, nullptr, 2048, 50048, 512, 50000);
}

// Round 6
// 964.134 us; speedup vs baseline: 1.4640x; 1.4640x over previous
//
#include <hip/hip_runtime.h>
#include <hip/hip_bf16.h>

using bf16 = __hip_bfloat16;
typedef __attribute__((ext_vector_type(8))) short short8;   // 8 bf16 = 4 VGPRs
typedef __attribute__((ext_vector_type(4))) float f32x4;    // MFMA C/D frag

#define MFMA_BF16(A,B,C) __builtin_amdgcn_mfma_f32_16x16x32_bf16((A),(B),(C),0,0,0)

static __device__ __forceinline__ unsigned bf16bits(float f) {
  union { bf16 h; unsigned short u; } cv; cv.h = __float2bfloat16(f); return cv.u;
}

// 16B device-coherent load: bypasses (stale) L1+L2, reads at LLC. MUST be
// followed by s_waitcnt vmcnt(0) + sched_barrier(0) before first use (#18).
static __device__ __forceinline__ short8 ldg16_sc1(const bf16* p) {
  short8 r;
  asm volatile("global_load_dwordx4 %0, %1, off sc0 sc1" : "=v"(r) : "v"(p));
  return r;
}

// async global->LDS, 16B per lane. LDS dest = wave-uniform base + lane*16.
static __device__ __forceinline__ void gload16(const void* g, void* l) {
  __builtin_amdgcn_global_load_lds(
      (const __attribute__((address_space(1))) void*)g,
      (__attribute__((address_space(3))) void*)l, 16, 0, 0);
}

// ---------------------------------------------------------------------------
// Generic bf16 GEMM: C[M,N] = A[M,K] @ B[N,K]^T (+bias)
// m97 structure: 128x128 tile, BK=32, 4 waves (2x2), 4x4 16x16x32 frags/wave.
// EPI 0: fp32 out, ld=Nreal.  EPI 1: tanh(x*BN_SCALE) -> bf16.
// EPI 2: g0p write — B is the ROW-PERMUTED Wih0 (n -> orig g*1024+b*4+hc),
//        output scattered to [b][t][r][q] (q=g*4+hc) for coalesced gate reads.
// ---------------------------------------------------------------------------
template<int EPI>
__global__ __launch_bounds__(256)
void gemm_bt(const bf16* __restrict__ A, const bf16* __restrict__ B,
             const float* __restrict__ bias1, const float* __restrict__ bias2,
             float* __restrict__ Cf, bf16* __restrict__ Cb,
             int M, int N, int K, int Nreal)
{
  __shared__ __align__(1024) bf16 As[128*32];
  __shared__ __align__(1024) bf16 Bs[128*32];
  const int tid  = threadIdx.x;
  const int wave = tid >> 6, lane = tid & 63;
  const int wr = wave >> 1, wc = wave & 1;
  const int row0 = blockIdx.y * 128;
  const int col0 = blockIdx.x * 128;

  f32x4 acc[4][4];
  #pragma unroll
  for (int m = 0; m < 4; ++m)
    #pragma unroll
    for (int n = 0; n < 4; ++n) { f32x4 z = {0.f,0.f,0.f,0.f}; acc[m][n] = z; }

  const int r_sub = lane >> 2;   // 0..15 (row within 16-row stage group)
  const int kc    = lane & 3;    // 16B chunk within 64B row

  for (int k0 = 0; k0 < K; k0 += 32) {
    __syncthreads();
    #pragma unroll
    for (int j = 0; j < 2; ++j) {
      const int rb = wave*32 + j*16;
      gload16(A + (size_t)(row0 + rb + r_sub)*K + k0 + kc*8,
              (void*)((char*)As + (size_t)rb*64));
      gload16(B + (size_t)(col0 + rb + r_sub)*K + k0 + kc*8,
              (void*)((char*)Bs + (size_t)rb*64));
    }
    __syncthreads();

    short8 af[4], bfv[4];
    #pragma unroll
    for (int m = 0; m < 4; ++m)
      af[m] = *(const short8*)(As + (wr*64 + m*16 + (lane&15))*32 + (lane>>4)*8);
    #pragma unroll
    for (int n = 0; n < 4; ++n)
      bfv[n] = *(const short8*)(Bs + (wc*64 + n*16 + (lane&15))*32 + (lane>>4)*8);
    #pragma unroll
    for (int m = 0; m < 4; ++m)
      #pragma unroll
      for (int n = 0; n < 4; ++n)
        acc[m][n] = MFMA_BF16(af[m], bfv[n], acc[m][n]);
  }

  const float BN_SCALE = 0.9999950000374997f;  // 1/sqrt(1+1e-5)
  #pragma unroll
  for (int m = 0; m < 4; ++m) {
    const int rg0 = row0 + wr*64 + m*16 + ((lane>>4)<<2);
    #pragma unroll
    for (int n = 0; n < 4; ++n) {
      const int cg = col0 + wc*64 + n*16 + (lane&15);
      if (EPI == 2) {
        const int bq = cg >> 4, q = cg & 15;
        const int orig = (q>>2)*1024 + bq*4 + (q&3);   // permuted -> original col
        const float bb = bias1[orig] + bias2[orig];
        #pragma unroll
        for (int j = 0; j < 4; ++j) {
          const int row = rg0 + j;
          Cf[((size_t)bq*64 + (row>>5))*512 + (size_t)(row&31)*16 + q]
              = acc[m][n][j] + bb;
        }
      } else if (cg < Nreal) {
        float bb = 0.f;
        if (bias1) bb += bias1[cg];
        if (bias2) bb += bias2[cg];
        #pragma unroll
        for (int j = 0; j < 4; ++j) {
          float v = acc[m][n][j] + bb;
          if (EPI == 1) {
            v = tanhf(v * BN_SCALE);
            Cb[(size_t)(rg0+j)*Nreal + cg] = __float2bfloat16(v);
          } else {
            Cf[(size_t)(rg0+j)*Nreal + cg] = v;
          }
        }
      }
    }
  }
}

// ---------------------------------------------------------------------------
// Persistent LSTM recurrence. 256 blocks x 256 threads, 1 block/CU.
// Weights: staged ONCE into LDS (96KB) -> zero per-step weight traffic.
// h traffic: 16B sc0+sc1 loads (LLC-coherent) + 8B relaxed agent stores.
// Barrier: per-block flag (64B apart); block b stores flag[b]=s+1 after a
// drain __syncthreads; ONLY wave 0 polls (4 flags/lane), waves 1-3 park at
// the closing __syncthreads. No fence in the loop; each (addr,value) is
// written once per call and read only after its flag is seen.
// ---------------------------------------------------------------------------
__global__ __launch_bounds__(256, 1)
void k_lstm_persist(const bf16* __restrict__ hinit, const float* __restrict__ cx,
                    const bf16* __restrict__ Wpack, const float* __restrict__ g0p,
                    const float* __restrict__ bih1, const float* __restrict__ bhh1,
                    bf16* __restrict__ h0_all, bf16* __restrict__ h1_all,
                    float* __restrict__ tail, unsigned* __restrict__ flags)
{
  const int b    = blockIdx.x;
  const int tid  = threadIdx.x;
  const int wave = tid >> 6, lane = tid & 63;

  __shared__ __align__(1024) bf16 Wlds[96*512];   // 96 KB: [chunk][lane][8]
  __shared__ float P[4][2][32][20];               // partial sums (padded)

  // one-time: stage this block's packed weights into LDS
  const bf16* wbase = Wpack + (size_t)b * 96 * 512;
  #pragma unroll
  for (int it = 0; it < 24; ++it) {
    const int chunk = it*4 + wave;                // wave-uniform
    gload16(wbase + (size_t)chunk*512 + lane*8,
            (void*)((char*)Wlds + (size_t)chunk*1024));
  }

  // gate/cell phase mapping: one LSTM cell per thread
  const int layer = tid >> 7;
  const int cell  = tid & 127;
  const int r     = cell >> 2;
  const int hc    = cell & 3;
  const int col   = b*4 + hc;
  float creg = cx[(size_t)layer*32768 + (size_t)r*1024 + col];
  float bsum[4];
  #pragma unroll
  for (int g = 0; g < 4; ++g)
    bsum[g] = (layer == 1) ? (bih1[g*1024 + col] + bhh1[g*1024 + col]) : 0.f;

  const int arow = lane & 15;
  const int koff = (lane >> 4) * 8;

  __syncthreads();   // weights staged (drains vmcnt incl. global_load_lds)

  for (int s = 0; s < 65; ++s) {
    const bf16* hA = (s == 0) ? hinit           : h0_all + (size_t)(s-1)*32768;
    const bf16* hB = (s <= 1) ? (hinit + 32768) : h1_all + (size_t)(s-2)*32768;

    // issue ALL h loads (32 x 16B sc1 per wave), then drain once
    short8 a0[8], a1[8], c0[8], c1[8];
    #pragma unroll
    for (int i = 0; i < 8; ++i) {
      const int kb = wave*256 + i*32 + koff;
      a0[i] = ldg16_sc1(hA + (size_t)arow*1024      + kb);
      a1[i] = ldg16_sc1(hA + (size_t)(arow+16)*1024 + kb);
      c0[i] = ldg16_sc1(hB + (size_t)arow*1024      + kb);
      c1[i] = ldg16_sc1(hB + (size_t)(arow+16)*1024 + kb);
    }
    float gpre[4] = {0.f, 0.f, 0.f, 0.f};
    if (layer == 0 && s < 64) {
      const float* gr = g0p + ((size_t)(b*64 + s)*32 + r)*16;
      #pragma unroll
      for (int g = 0; g < 4; ++g) gpre[g] = gr[g*4 + hc];
    }
    asm volatile("s_waitcnt vmcnt(0)" ::: "memory");
    __builtin_amdgcn_sched_barrier(0);          // rule #18: pin MFMAs after

    f32x4 z = {0.f,0.f,0.f,0.f};
    f32x4 acc00 = z, acc01 = z, acc10 = z, acc11 = z;
    #pragma unroll
    for (int i = 0; i < 8; ++i) {
      const int ks = wave*8 + i;
      short8 w0 = *(const short8*)(Wlds + ((size_t)(     ks)*64 + lane)*8);
      short8 w1 = *(const short8*)(Wlds + ((size_t)(32 + ks)*64 + lane)*8);
      short8 w2 = *(const short8*)(Wlds + ((size_t)(64 + ks)*64 + lane)*8);
      acc00 = MFMA_BF16(a0[i], w0, acc00);   // layer0: Whh0 @ h0[s-1]
      acc01 = MFMA_BF16(a1[i], w0, acc01);
      acc10 = MFMA_BF16(a0[i], w1, acc10);   // layer1: Wih1 @ h0[s-1]
      acc11 = MFMA_BF16(a1[i], w1, acc11);
      acc10 = MFMA_BF16(c0[i], w2, acc10);   // layer1 += Whh1 @ h1[s-2]
      acc11 = MFMA_BF16(c1[i], w2, acc11);
    }

    #pragma unroll
    for (int j = 0; j < 4; ++j) {
      const int pr = (lane >> 4)*4 + j;
      P[wave][0][pr     ][lane & 15] = acc00[j];
      P[wave][0][pr + 16][lane & 15] = acc01[j];
      P[wave][1][pr     ][lane & 15] = acc10[j];
      P[wave][1][pr + 16][lane & 15] = acc11[j];
    }
    __syncthreads();                         // #1: P complete

    const int t = s - layer;
    if (t >= 0 && t < 64) {
      float v[4];
      #pragma unroll
      for (int g = 0; g < 4; ++g) {
        const int j = g*4 + hc;
        v[g] = P[0][layer][r][j] + P[1][layer][r][j]
             + P[2][layer][r][j] + P[3][layer][r][j] + bsum[g] + gpre[g];
      }
      const float iv = 1.f/(1.f + expf(-v[0]));
      const float fv = 1.f/(1.f + expf(-v[1]));
      const float gv = tanhf(v[2]);
      const float ov = 1.f/(1.f + expf(-v[3]));
      creg = fv*creg + iv*gv;
      const float hn = ov*tanhf(creg);
      // gather 4 cells -> one 8B agent-relaxed store (cols b*4..b*4+3)
      unsigned hu  = bf16bits(hn);
      unsigned p01 = hu | ((unsigned)__shfl_xor((int)hu, 1) << 16);
      unsigned p23 = (unsigned)__shfl_xor((int)p01, 2);
      if (hc == 0) {
        bf16* hp = (layer ? h1_all : h0_all) + (size_t)t*32768 + (size_t)r*1024 + b*4;
        unsigned long long v64 = (unsigned long long)p01
                               | ((unsigned long long)p23 << 32);
        __hip_atomic_store((unsigned long long*)hp, v64,
                           __ATOMIC_RELAXED, __HIP_MEMORY_SCOPE_AGENT);
      }
      if (t == 63) {
        tail[(size_t)layer*32768 + (size_t)r*1024 + col]         = hn;
        tail[65536 + (size_t)layer*32768 + (size_t)r*1024 + col] = creg;
      }
    }
    if (s == 64) break;

    __syncthreads();                         // #2: drain h publishes (vmcnt 0)
    if (tid == 0)
      __hip_atomic_store(flags + b*16, (unsigned)(s + 1),
                         __ATOMIC_RELEASE, __HIP_MEMORY_SCOPE_AGENT);
    if (wave == 0) {                         // only wave 0 polls
      const unsigned su = (unsigned)s;
      for (;;) {
        unsigned v0 = __hip_atomic_load(flags + (lane*4+0)*16, __ATOMIC_RELAXED, __HIP_MEMORY_SCOPE_AGENT);
        unsigned v1 = __hip_atomic_load(flags + (lane*4+1)*16, __ATOMIC_RELAXED, __HIP_MEMORY_SCOPE_AGENT);
        unsigned v2 = __hip_atomic_load(flags + (lane*4+2)*16, __ATOMIC_RELAXED, __HIP_MEMORY_SCOPE_AGENT);
        unsigned v3 = __hip_atomic_load(flags + (lane*4+3)*16, __ATOMIC_RELAXED, __HIP_MEMORY_SCOPE_AGENT);
        bool ok = (v0 > su) & (v1 > su) & (v2 > su) & (v3 > su);
        if (__all(ok)) break;
        __builtin_amdgcn_s_sleep(2);
      }
    }
    __syncthreads();                         // #3: release all waves
  }
}

// ---------------------------------------------------------------------------
// Pack Whh0 / Wih1 / Whh1 into per-block MFMA-fragment order (bf16).
// ---------------------------------------------------------------------------
__global__ __launch_bounds__(256)
void k_pack(const float* __restrict__ Whh0, const float* __restrict__ Wih1,
            const float* __restrict__ Whh1, bf16* __restrict__ Wpack)
{
  const int b = blockIdx.x;
  #pragma unroll 4
  for (int it = 0; it < 24; ++it) {
    const int idx = it*256 + threadIdx.x;
    const int chunkp = idx >> 6;            // 0..95
    const int l = idx & 63;
    const int p = chunkp >> 5, c = chunkp & 31;
    const float* W = (p == 0) ? Whh0 : (p == 1 ? Wih1 : Whh1);
    const int j = l & 15;
    const int row = (j>>2)*1024 + b*4 + (j&3);
    const int k = c*32 + (l>>4)*8;
    const float* src = W + (size_t)row*1024 + k;
    bf16* dst = Wpack + ((size_t)(b*96 + chunkp)*64 + l)*8;
    #pragma unroll
    for (int q = 0; q < 8; ++q) dst[q] = __float2bfloat16(src[q]);
  }
}

// ---------------------------------------------------------------------------
// small helpers
// ---------------------------------------------------------------------------
__global__ void k_cvt(const float* __restrict__ s, bf16* __restrict__ d, long n) {
  long i = (long)blockIdx.x*blockDim.x + threadIdx.x;
  if (i < n) d[i] = __float2bfloat16(s[i]);
}

// Wih0 cast with ROW PERMUTATION: dst row n <- src row ((n>>2)&3)*1024 + (n>>4)*4 + (n&3)
__global__ void k_cvt_perm(const float* __restrict__ src, bf16* __restrict__ dst) {
  const int n = blockIdx.x;                 // 0..4095 (permuted row)
  const int orig = ((n>>2)&3)*1024 + (n>>4)*4 + (n&3);
  const float4 v = ((const float4*)(src + (size_t)orig*512))[threadIdx.x];
  bf16* d = dst + (size_t)n*512 + threadIdx.x*4;
  d[0] = __float2bfloat16(v.x); d[1] = __float2bfloat16(v.y);
  d[2] = __float2bfloat16(v.z); d[3] = __float2bfloat16(v.w);
}

__global__ void k_cvt_pad(const float* __restrict__ s, bf16* __restrict__ d,
                          long n, long nrows_real, int rowlen) {
  long i = (long)blockIdx.x*blockDim.x + threadIdx.x;
  if (i < n) {
    long r = i / rowlen;
    d[i] = (r < nrows_real) ? __float2bfloat16(s[i]) : __float2bfloat16(0.f);
  }
}

__global__ void k_init(const float* __restrict__ hx, bf16* __restrict__ hinit,
                       unsigned* __restrict__ flags) {
  int i = blockIdx.x*blockDim.x + threadIdx.x;
  if (i < 4096) flags[i] = 0u;
  if (i < 65536) hinit[i] = __float2bfloat16(hx[i]);
}

__global__ void k_embed(const int* __restrict__ ids, const float* __restrict__ emb_w,
                        bf16* __restrict__ out) {
  const int row = blockIdx.x;
  const int tok = ids[row];
  const float4 v = ((const float4*)(emb_w + (size_t)tok*512))[threadIdx.x];
  bf16* d = out + (size_t)row*512 + threadIdx.x*4;
  d[0] = __float2bfloat16(v.x); d[1] = __float2bfloat16(v.y);
  d[2] = __float2bfloat16(v.z); d[3] = __float2bfloat16(v.w);
}

// ---------------------------------------------------------------------------
extern "C" void kernel_launch(void* const* d_in, const int* in_sizes, int n_in,
                              void* d_out, int out_size, void* d_ws, size_t ws_size,
                              hipStream_t stream) {
  const int*   ids  = (const int*)d_in[0];
  const float* hx   = (const float*)d_in[1];
  const float* cx   = (const float*)d_in[2];
  const float* embw = (const float*)d_in[3];
  const float* Wih0 = (const float*)d_in[4];
  const float* Whh0 = (const float*)d_in[5];
  const float* bih0 = (const float*)d_in[6];
  const float* bhh0 = (const float*)d_in[7];
  const float* Wih1 = (const float*)d_in[8];
  const float* Whh1 = (const float*)d_in[9];
  const float* bih1 = (const float*)d_in[10];
  const float* bhh1 = (const float*)d_in[11];
  const float* Wp   = (const float*)d_in[12];
  const float* bp   = (const float*)d_in[13];
  const float* Wd   = (const float*)d_in[14];
  const float* bd   = (const float*)d_in[15];
  float* out = (float*)d_out;

  char* w = (char*)d_ws;
  bf16* Wih0b = (bf16*)w; w += 4096l*512*2;       // permuted rows
  bf16* Wpack = (bf16*)w; w += 256l*96*64*8*2;    // 24 MB packed recurrent weights
  bf16* Wpb   = (bf16*)w; w += 512l*1024*2;
  bf16* Wdb   = (bf16*)w; w += 50048l*512*2;
  bf16* embb  = (bf16*)w; w += 2048l*512*2;
  float* g0p  = (float*)w; w += 2048l*4096*4;     // [b][t][r][q] layout
  bf16* h0a   = (bf16*)w; w += 2048l*1024*2;
  bf16* h1a   = (bf16*)w; w += 2048l*1024*2;
  bf16* hinit = (bf16*)w; w += 2l*32*1024*2;
  bf16* pb    = (bf16*)w; w += 2048l*512*2;
  unsigned* flags = (unsigned*)w; w += 4096*4;

  k_cvt_perm<<<4096, 128, 0, stream>>>(Wih0, Wih0b);
  k_cvt<<<(512l*1024 + 255)/256, 256, 0, stream>>>(Wp, Wpb, 512l*1024);
  k_cvt_pad<<<(50048l*512 + 255)/256, 256, 0, stream>>>(Wd, Wdb, 50048l*512, 50000, 512);
  k_init<<<256, 256, 0, stream>>>(hx, hinit, flags);
  k_embed<<<2048, 128, 0, stream>>>(ids, embw, embb);
  k_pack<<<256, 256, 0, stream>>>(Whh0, Wih1, Whh1, Wpack);

  // layer-0 input-side GEMM for ALL timesteps -> g0p layout; folds bih0+bhh0
  gemm_bt<2><<<dim3(32, 16), 256, 0, stream>>>(
      embb, Wih0b, bih0, bhh0, g0p, nullptr, 2048, 4096, 512, 4096);

  // persistent pipelined recurrence: one dispatch, 65 super-steps
  float* tail = out + 102400000l;
  k_lstm_persist<<<256, 256, 0, stream>>>(hinit, cx, Wpack, g0p, bih1, bhh1,
                                          h0a, h1a, tail, flags);

  // predictor: Linear + BN(eval) + tanh -> bf16
  gemm_bt<1><<<dim3(4, 16), 256, 0, stream>>>(
      h1a, Wpb, bp, nullptr, nullptr, pb, 2048, 512, 1024, 512);

  // decoder: [2048,512] @ [50048,512]^T (padded), guarded store to 50000
  gemm_bt<0><<<dim3(391, 16), 256, 0, stream>>>(
      pb, Wdb, bd, nullptr, out, nullptr, 2048, 50048, 512, 50000);
}

// Round 7
// 903.375 us; speedup vs baseline: 1.5624x; 1.0673x over previous
//
#include <hip/hip_runtime.h>
#include <hip/hip_bf16.h>

using bf16 = __hip_bfloat16;
typedef __attribute__((ext_vector_type(8))) short short8;   // 8 bf16 = 4 VGPRs
typedef __attribute__((ext_vector_type(4))) float f32x4;    // MFMA C/D frag

#define MFMA_BF16(A,B,C) __builtin_amdgcn_mfma_f32_16x16x32_bf16((A),(B),(C),0,0,0)

static __device__ __forceinline__ unsigned bf16bits(float f) {
  union { bf16 h; unsigned short u; } cv; cv.h = __float2bfloat16(f); return cv.u;
}

// async global->LDS, 16B per lane. LDS dest = wave-uniform base + lane*16.
static __device__ __forceinline__ void gload16(const void* g, void* l) {
  __builtin_amdgcn_global_load_lds(
      (const __attribute__((address_space(1))) void*)g,
      (__attribute__((address_space(3))) void*)l, 16, 0, 0);
}

// ---------------------------------------------------------------------------
// Generic bf16 GEMM: C[M,N] = A[M,K] @ B[N,K]^T (+bias)
// m97 structure: 128x128 tile, BK=32, 4 waves (2x2), 4x4 16x16x32 frags/wave.
// EPI 0: fp32 out, ld=Nreal.  EPI 1: tanh(x*BN_SCALE) -> bf16.
// EPI 2: g0p write — B is the ROW-PERMUTED Wih0 (n -> orig g*1024+b*4+hc),
//        output scattered to [b][t][r][q] (q=g*4+hc) for coalesced gate reads.
// ---------------------------------------------------------------------------
template<int EPI>
__global__ __launch_bounds__(256)
void gemm_bt(const bf16* __restrict__ A, const bf16* __restrict__ B,
             const float* __restrict__ bias1, const float* __restrict__ bias2,
             float* __restrict__ Cf, bf16* __restrict__ Cb,
             int M, int N, int K, int Nreal)
{
  __shared__ __align__(1024) bf16 As[128*32];
  __shared__ __align__(1024) bf16 Bs[128*32];
  const int tid  = threadIdx.x;
  const int wave = tid >> 6, lane = tid & 63;
  const int wr = wave >> 1, wc = wave & 1;
  const int row0 = blockIdx.y * 128;
  const int col0 = blockIdx.x * 128;

  f32x4 acc[4][4];
  #pragma unroll
  for (int m = 0; m < 4; ++m)
    #pragma unroll
    for (int n = 0; n < 4; ++n) { f32x4 z = {0.f,0.f,0.f,0.f}; acc[m][n] = z; }

  const int r_sub = lane >> 2;   // 0..15 (row within 16-row stage group)
  const int kc    = lane & 3;    // 16B chunk within 64B row

  for (int k0 = 0; k0 < K; k0 += 32) {
    __syncthreads();
    #pragma unroll
    for (int j = 0; j < 2; ++j) {
      const int rb = wave*32 + j*16;
      gload16(A + (size_t)(row0 + rb + r_sub)*K + k0 + kc*8,
              (void*)((char*)As + (size_t)rb*64));
      gload16(B + (size_t)(col0 + rb + r_sub)*K + k0 + kc*8,
              (void*)((char*)Bs + (size_t)rb*64));
    }
    __syncthreads();

    short8 af[4], bfv[4];
    #pragma unroll
    for (int m = 0; m < 4; ++m)
      af[m] = *(const short8*)(As + (wr*64 + m*16 + (lane&15))*32 + (lane>>4)*8);
    #pragma unroll
    for (int n = 0; n < 4; ++n)
      bfv[n] = *(const short8*)(Bs + (wc*64 + n*16 + (lane&15))*32 + (lane>>4)*8);
    #pragma unroll
    for (int m = 0; m < 4; ++m)
      #pragma unroll
      for (int n = 0; n < 4; ++n)
        acc[m][n] = MFMA_BF16(af[m], bfv[n], acc[m][n]);
  }

  const float BN_SCALE = 0.9999950000374997f;  // 1/sqrt(1+1e-5)
  #pragma unroll
  for (int m = 0; m < 4; ++m) {
    const int rg0 = row0 + wr*64 + m*16 + ((lane>>4)<<2);
    #pragma unroll
    for (int n = 0; n < 4; ++n) {
      const int cg = col0 + wc*64 + n*16 + (lane&15);
      if (EPI == 2) {
        const int bq = cg >> 4, q = cg & 15;
        const int orig = (q>>2)*1024 + bq*4 + (q&3);   // permuted -> original col
        const float bb = bias1[orig] + bias2[orig];
        #pragma unroll
        for (int j = 0; j < 4; ++j) {
          const int row = rg0 + j;
          Cf[((size_t)bq*64 + (row>>5))*512 + (size_t)(row&31)*16 + q]
              = acc[m][n][j] + bb;
        }
      } else if (cg < Nreal) {
        float bb = 0.f;
        if (bias1) bb += bias1[cg];
        if (bias2) bb += bias2[cg];
        #pragma unroll
        for (int j = 0; j < 4; ++j) {
          float v = acc[m][n][j] + bb;
          if (EPI == 1) {
            v = tanhf(v * BN_SCALE);
            Cb[(size_t)(rg0+j)*Nreal + cg] = __float2bfloat16(v);
          } else {
            Cf[(size_t)(rg0+j)*Nreal + cg] = v;
          }
        }
      }
    }
  }
}

// ---------------------------------------------------------------------------
// Persistent LSTM recurrence. 256 blocks x 256 threads, 1 block/CU.
// Weights: LDS (96KB, staged once). h reads: NORMAL CACHED loads -> the
// per-XCD L2 acts as a broadcast cache (LLC traffic 32x lower than sc1
// loads). Safe because each h address is write-once (sc1 store straight to
// LLC), read only after its producer's flag, and never L2-cached earlier in
// the run (dispatch-start invalidates L2 — empirically proven by g0p, which
// crosses a kernel boundary the same way). Compiler hoist of h loads above
// the flag wait is fenced (asm memory + sched_barrier); HW issues VMEM in
// program order after the barrier release.
// Barrier: per-block flag on its own 128B line; wave 0 polls 4 flags/lane.
// ---------------------------------------------------------------------------
__global__ __launch_bounds__(256, 1)
void k_lstm_persist(const bf16* __restrict__ hinit, const float* __restrict__ cx,
                    const bf16* __restrict__ Wpack, const float* __restrict__ g0p,
                    const float* __restrict__ bih1, const float* __restrict__ bhh1,
                    bf16* __restrict__ h0_all, bf16* __restrict__ h1_all,
                    float* __restrict__ tail, unsigned* __restrict__ flags)
{
  const int b    = blockIdx.x;
  const int tid  = threadIdx.x;
  const int wave = tid >> 6, lane = tid & 63;

  __shared__ __align__(1024) bf16 Wlds[96*512];   // 96 KB: [chunk][lane][8]
  __shared__ float P[4][2][32][20];               // partial sums (padded)

  // one-time: stage this block's packed weights into LDS
  const bf16* wbase = Wpack + (size_t)b * 96 * 512;
  #pragma unroll
  for (int it = 0; it < 24; ++it) {
    const int chunk = it*4 + wave;                // wave-uniform
    gload16(wbase + (size_t)chunk*512 + lane*8,
            (void*)((char*)Wlds + (size_t)chunk*1024));
  }

  // gate/cell phase mapping: one LSTM cell per thread
  const int layer = tid >> 7;
  const int cell  = tid & 127;
  const int r     = cell >> 2;
  const int hc    = cell & 3;
  const int col   = b*4 + hc;
  float creg = cx[(size_t)layer*32768 + (size_t)r*1024 + col];
  float bsum[4];
  #pragma unroll
  for (int g = 0; g < 4; ++g)
    bsum[g] = (layer == 1) ? (bih1[g*1024 + col] + bhh1[g*1024 + col]) : 0.f;

  const int arow = lane & 15;
  const int koff = (lane >> 4) * 8;

  __syncthreads();   // weights staged (drains vmcnt incl. global_load_lds)

  for (int s = 0; s < 65; ++s) {
    const bf16* hA = (s == 0) ? hinit           : h0_all + (size_t)(s-1)*32768;
    const bf16* hB = (s <= 1) ? (hinit + 32768) : h1_all + (size_t)(s-2)*32768;

    // normal cached h loads (L2 broadcast); all issued up front
    short8 a0[8], a1[8], c0[8], c1[8];
    #pragma unroll
    for (int i = 0; i < 8; ++i) {
      const int kb = wave*256 + i*32 + koff;
      a0[i] = *(const short8*)(hA + (size_t)arow*1024      + kb);
      a1[i] = *(const short8*)(hA + (size_t)(arow+16)*1024 + kb);
      c0[i] = *(const short8*)(hB + (size_t)arow*1024      + kb);
      c1[i] = *(const short8*)(hB + (size_t)(arow+16)*1024 + kb);
    }
    float gpre[4] = {0.f, 0.f, 0.f, 0.f};
    if (layer == 0 && s < 64) {
      const float* gr = g0p + ((size_t)(b*64 + s)*32 + r)*16;
      #pragma unroll
      for (int g = 0; g < 4; ++g) gpre[g] = gr[g*4 + hc];
    }

    f32x4 z = {0.f,0.f,0.f,0.f};
    f32x4 acc00 = z, acc01 = z, acc10 = z, acc11 = z;
    #pragma unroll
    for (int i = 0; i < 8; ++i) {
      const int ks = wave*8 + i;
      short8 w0 = *(const short8*)(Wlds + ((size_t)(     ks)*64 + lane)*8);
      short8 w1 = *(const short8*)(Wlds + ((size_t)(32 + ks)*64 + lane)*8);
      short8 w2 = *(const short8*)(Wlds + ((size_t)(64 + ks)*64 + lane)*8);
      acc00 = MFMA_BF16(a0[i], w0, acc00);   // layer0: Whh0 @ h0[s-1]
      acc01 = MFMA_BF16(a1[i], w0, acc01);
      acc10 = MFMA_BF16(a0[i], w1, acc10);   // layer1: Wih1 @ h0[s-1]
      acc11 = MFMA_BF16(a1[i], w1, acc11);
      acc10 = MFMA_BF16(c0[i], w2, acc10);   // layer1 += Whh1 @ h1[s-2]
      acc11 = MFMA_BF16(c1[i], w2, acc11);
    }

    #pragma unroll
    for (int j = 0; j < 4; ++j) {
      const int pr = (lane >> 4)*4 + j;
      P[wave][0][pr     ][lane & 15] = acc00[j];
      P[wave][0][pr + 16][lane & 15] = acc01[j];
      P[wave][1][pr     ][lane & 15] = acc10[j];
      P[wave][1][pr + 16][lane & 15] = acc11[j];
    }
    __syncthreads();                         // #1: P complete

    const int t = s - layer;
    if (t >= 0 && t < 64) {
      float v[4];
      #pragma unroll
      for (int g = 0; g < 4; ++g) {
        const int j = g*4 + hc;
        v[g] = P[0][layer][r][j] + P[1][layer][r][j]
             + P[2][layer][r][j] + P[3][layer][r][j] + bsum[g] + gpre[g];
      }
      const float iv = 1.f/(1.f + expf(-v[0]));
      const float fv = 1.f/(1.f + expf(-v[1]));
      const float gv = tanhf(v[2]);
      const float ov = 1.f/(1.f + expf(-v[3]));
      creg = fv*creg + iv*gv;
      const float hn = ov*tanhf(creg);
      // gather 4 cells -> one 8B agent-relaxed store straight to LLC
      unsigned hu  = bf16bits(hn);
      unsigned p01 = hu | ((unsigned)__shfl_xor((int)hu, 1) << 16);
      unsigned p23 = (unsigned)__shfl_xor((int)p01, 2);
      if (hc == 0) {
        bf16* hp = (layer ? h1_all : h0_all) + (size_t)t*32768 + (size_t)r*1024 + b*4;
        unsigned long long v64 = (unsigned long long)p01
                               | ((unsigned long long)p23 << 32);
        __hip_atomic_store((unsigned long long*)hp, v64,
                           __ATOMIC_RELAXED, __HIP_MEMORY_SCOPE_AGENT);
      }
      if (t == 63) {
        tail[(size_t)layer*32768 + (size_t)r*1024 + col]         = hn;
        tail[65536 + (size_t)layer*32768 + (size_t)r*1024 + col] = creg;
      }
    }
    if (s == 64) break;

    __syncthreads();                         // #2: drain h publishes (vmcnt 0)
    if (tid == 0)
      __hip_atomic_store(flags + b*32, (unsigned)(s + 1),
                         __ATOMIC_RELEASE, __HIP_MEMORY_SCOPE_AGENT);
    if (wave == 0) {                         // only wave 0 polls
      const unsigned su = (unsigned)s;
      for (;;) {
        unsigned v0 = __hip_atomic_load(flags + (lane*4+0)*32, __ATOMIC_RELAXED, __HIP_MEMORY_SCOPE_AGENT);
        unsigned v1 = __hip_atomic_load(flags + (lane*4+1)*32, __ATOMIC_RELAXED, __HIP_MEMORY_SCOPE_AGENT);
        unsigned v2 = __hip_atomic_load(flags + (lane*4+2)*32, __ATOMIC_RELAXED, __HIP_MEMORY_SCOPE_AGENT);
        unsigned v3 = __hip_atomic_load(flags + (lane*4+3)*32, __ATOMIC_RELAXED, __HIP_MEMORY_SCOPE_AGENT);
        bool ok = (v0 > su) & (v1 > su) & (v2 > su) & (v3 > su);
        if (__all(ok)) break;
        __builtin_amdgcn_s_sleep(1);
      }
    }
    __syncthreads();                         // #3: release all waves
    asm volatile("" ::: "memory");           // no hoisting of h loads above
    __builtin_amdgcn_sched_barrier(0);
  }
}

// ---------------------------------------------------------------------------
// Pack Whh0 / Wih1 / Whh1 into per-block MFMA-fragment order (bf16).
// ---------------------------------------------------------------------------
__global__ __launch_bounds__(256)
void k_pack(const float* __restrict__ Whh0, const float* __restrict__ Wih1,
            const float* __restrict__ Whh1, bf16* __restrict__ Wpack)
{
  const int b = blockIdx.x;
  #pragma unroll 4
  for (int it = 0; it < 24; ++it) {
    const int idx = it*256 + threadIdx.x;
    const int chunkp = idx >> 6;            // 0..95
    const int l = idx & 63;
    const int p = chunkp >> 5, c = chunkp & 31;
    const float* W = (p == 0) ? Whh0 : (p == 1 ? Wih1 : Whh1);
    const int j = l & 15;
    const int row = (j>>2)*1024 + b*4 + (j&3);
    const int k = c*32 + (l>>4)*8;
    const float* src = W + (size_t)row*1024 + k;
    bf16* dst = Wpack + ((size_t)(b*96 + chunkp)*64 + l)*8;
    #pragma unroll
    for (int q = 0; q < 8; ++q) dst[q] = __float2bfloat16(src[q]);
  }
}

// ---------------------------------------------------------------------------
// small helpers
// ---------------------------------------------------------------------------
__global__ void k_cvt(const float* __restrict__ s, bf16* __restrict__ d, long n) {
  long i = (long)blockIdx.x*blockDim.x + threadIdx.x;
  if (i < n) d[i] = __float2bfloat16(s[i]);
}

// Wih0 cast with ROW PERMUTATION: dst row n <- src row ((n>>2)&3)*1024 + (n>>4)*4 + (n&3)
__global__ void k_cvt_perm(const float* __restrict__ src, bf16* __restrict__ dst) {
  const int n = blockIdx.x;                 // 0..4095 (permuted row)
  const int orig = ((n>>2)&3)*1024 + (n>>4)*4 + (n&3);
  const float4 v = ((const float4*)(src + (size_t)orig*512))[threadIdx.x];
  bf16* d = dst + (size_t)n*512 + threadIdx.x*4;
  d[0] = __float2bfloat16(v.x); d[1] = __float2bfloat16(v.y);
  d[2] = __float2bfloat16(v.z); d[3] = __float2bfloat16(v.w);
}

__global__ void k_cvt_pad(const float* __restrict__ s, bf16* __restrict__ d,
                          long n, long nrows_real, int rowlen) {
  long i = (long)blockIdx.x*blockDim.x + threadIdx.x;
  if (i < n) {
    long r = i / rowlen;
    d[i] = (r < nrows_real) ? __float2bfloat16(s[i]) : __float2bfloat16(0.f);
  }
}

__global__ void k_init(const float* __restrict__ hx, bf16* __restrict__ hinit,
                       unsigned* __restrict__ flags) {
  int i = blockIdx.x*blockDim.x + threadIdx.x;
  if (i < 8192) flags[i] = 0u;
  if (i < 65536) hinit[i] = __float2bfloat16(hx[i]);
}

__global__ void k_embed(const int* __restrict__ ids, const float* __restrict__ emb_w,
                        bf16* __restrict__ out) {
  const int row = blockIdx.x;
  const int tok = ids[row];
  const float4 v = ((const float4*)(emb_w + (size_t)tok*512))[threadIdx.x];
  bf16* d = out + (size_t)row*512 + threadIdx.x*4;
  d[0] = __float2bfloat16(v.x); d[1] = __float2bfloat16(v.y);
  d[2] = __float2bfloat16(v.z); d[3] = __float2bfloat16(v.w);
}

// ---------------------------------------------------------------------------
extern "C" void kernel_launch(void* const* d_in, const int* in_sizes, int n_in,
                              void* d_out, int out_size, void* d_ws, size_t ws_size,
                              hipStream_t stream) {
  const int*   ids  = (const int*)d_in[0];
  const float* hx   = (const float*)d_in[1];
  const float* cx   = (const float*)d_in[2];
  const float* embw = (const float*)d_in[3];
  const float* Wih0 = (const float*)d_in[4];
  const float* Whh0 = (const float*)d_in[5];
  const float* bih0 = (const float*)d_in[6];
  const float* bhh0 = (const float*)d_in[7];
  const float* Wih1 = (const float*)d_in[8];
  const float* Whh1 = (const float*)d_in[9];
  const float* bih1 = (const float*)d_in[10];
  const float* bhh1 = (const float*)d_in[11];
  const float* Wp   = (const float*)d_in[12];
  const float* bp   = (const float*)d_in[13];
  const float* Wd   = (const float*)d_in[14];
  const float* bd   = (const float*)d_in[15];
  float* out = (float*)d_out;

  char* w = (char*)d_ws;
  bf16* Wih0b = (bf16*)w; w += 4096l*512*2;       // permuted rows
  bf16* Wpack = (bf16*)w; w += 256l*96*64*8*2;    // 24 MB packed recurrent weights
  bf16* Wpb   = (bf16*)w; w += 512l*1024*2;
  bf16* Wdb   = (bf16*)w; w += 50048l*512*2;
  bf16* embb  = (bf16*)w; w += 2048l*512*2;
  float* g0p  = (float*)w; w += 2048l*4096*4;     // [b][t][r][q] layout
  bf16* h0a   = (bf16*)w; w += 2048l*1024*2;
  bf16* h1a   = (bf16*)w; w += 2048l*1024*2;
  bf16* hinit = (bf16*)w; w += 2l*32*1024*2;
  bf16* pb    = (bf16*)w; w += 2048l*512*2;
  unsigned* flags = (unsigned*)w; w += 8192*4;

  k_cvt_perm<<<4096, 128, 0, stream>>>(Wih0, Wih0b);
  k_cvt<<<(512l*1024 + 255)/256, 256, 0, stream>>>(Wp, Wpb, 512l*1024);
  k_cvt_pad<<<(50048l*512 + 255)/256, 256, 0, stream>>>(Wd, Wdb, 50048l*512, 50000, 512);
  k_init<<<256, 256, 0, stream>>>(hx, hinit, flags);
  k_embed<<<2048, 128, 0, stream>>>(ids, embw, embb);
  k_pack<<<256, 256, 0, stream>>>(Whh0, Wih1, Whh1, Wpack);

  // layer-0 input-side GEMM for ALL timesteps -> g0p layout; folds bih0+bhh0
  gemm_bt<2><<<dim3(32, 16), 256, 0, stream>>>(
      embb, Wih0b, bih0, bhh0, g0p, nullptr, 2048, 4096, 512, 4096);

  // persistent pipelined recurrence: one dispatch, 65 super-steps
  float* tail = out + 102400000l;
  k_lstm_persist<<<256, 256, 0, stream>>>(hinit, cx, Wpack, g0p, bih1, bhh1,
                                          h0a, h1a, tail, flags);

  // predictor: Linear + BN(eval) + tanh -> bf16
  gemm_bt<1><<<dim3(4, 16), 256, 0, stream>>>(
      h1a, Wpb, bp, nullptr, nullptr, pb, 2048, 512, 1024, 512);

  // decoder: [2048,512] @ [50048,512]^T (padded), guarded store to 50000
  gemm_bt<0><<<dim3(391, 16), 256, 0, stream>>>(
      pb, Wdb, bd, nullptr, out, nullptr, 2048, 50048, 512, 50000);
}

// Round 9
// 736.569 us; speedup vs baseline: 1.9162x; 1.2265x over previous
//
#include <hip/hip_runtime.h>
#include <hip/hip_bf16.h>

using bf16 = __hip_bfloat16;
typedef __attribute__((ext_vector_type(8))) short short8;   // 8 bf16 = 4 VGPRs
typedef __attribute__((ext_vector_type(4))) float f32x4;    // MFMA C/D frag

#define MFMA_BF16(A,B,C) __builtin_amdgcn_mfma_f32_16x16x32_bf16((A),(B),(C),0,0,0)

static __device__ __forceinline__ unsigned bf16bits(float f) {
  union { bf16 h; unsigned short u; } cv; cv.h = __float2bfloat16(f); return cv.u;
}

// async global->LDS, 16B per lane. LDS dest = wave-uniform base + lane*16.
static __device__ __forceinline__ void gload16(const void* g, void* l) {
  __builtin_amdgcn_global_load_lds(
      (const __attribute__((address_space(1))) void*)g,
      (__attribute__((address_space(3))) void*)l, 16, 0, 0);
}

// ---------------------------------------------------------------------------
// Generic bf16 GEMM: C[M,N] = A[M,K] @ B[N,K]^T (+bias)
// m97 structure: 128x128 tile, BK=32, 4 waves (2x2), 4x4 16x16x32 frags/wave.
// EPI 0: fp32 out, ld=Nreal.  EPI 1: tanh(x*BN_SCALE) -> bf16.
// EPI 2: g0p write — B is the ROW-PERMUTED Wih0 (n -> orig g*1024+b*4+hc),
//        output scattered to [b][t][r][q] (q=g*4+hc) for coalesced gate reads.
// ---------------------------------------------------------------------------
template<int EPI>
__global__ __launch_bounds__(256)
void gemm_bt(const bf16* __restrict__ A, const bf16* __restrict__ B,
             const float* __restrict__ bias1, const float* __restrict__ bias2,
             float* __restrict__ Cf, bf16* __restrict__ Cb,
             int M, int N, int K, int Nreal)
{
  __shared__ __align__(1024) bf16 As[128*32];
  __shared__ __align__(1024) bf16 Bs[128*32];
  const int tid  = threadIdx.x;
  const int wave = tid >> 6, lane = tid & 63;
  const int wr = wave >> 1, wc = wave & 1;
  const int row0 = blockIdx.y * 128;
  const int col0 = blockIdx.x * 128;

  f32x4 acc[4][4];
  #pragma unroll
  for (int m = 0; m < 4; ++m)
    #pragma unroll
    for (int n = 0; n < 4; ++n) { f32x4 z = {0.f,0.f,0.f,0.f}; acc[m][n] = z; }

  const int r_sub = lane >> 2;   // 0..15 (row within 16-row stage group)
  const int kc    = lane & 3;    // 16B chunk within 64B row

  for (int k0 = 0; k0 < K; k0 += 32) {
    __syncthreads();
    #pragma unroll
    for (int j = 0; j < 2; ++j) {
      const int rb = wave*32 + j*16;
      gload16(A + (size_t)(row0 + rb + r_sub)*K + k0 + kc*8,
              (void*)((char*)As + (size_t)rb*64));
      gload16(B + (size_t)(col0 + rb + r_sub)*K + k0 + kc*8,
              (void*)((char*)Bs + (size_t)rb*64));
    }
    __syncthreads();

    short8 af[4], bfv[4];
    #pragma unroll
    for (int m = 0; m < 4; ++m)
      af[m] = *(const short8*)(As + (wr*64 + m*16 + (lane&15))*32 + (lane>>4)*8);
    #pragma unroll
    for (int n = 0; n < 4; ++n)
      bfv[n] = *(const short8*)(Bs + (wc*64 + n*16 + (lane&15))*32 + (lane>>4)*8);
    #pragma unroll
    for (int m = 0; m < 4; ++m)
      #pragma unroll
      for (int n = 0; n < 4; ++n)
        acc[m][n] = MFMA_BF16(af[m], bfv[n], acc[m][n]);
  }

  const float BN_SCALE = 0.9999950000374997f;  // 1/sqrt(1+1e-5)
  #pragma unroll
  for (int m = 0; m < 4; ++m) {
    const int rg0 = row0 + wr*64 + m*16 + ((lane>>4)<<2);
    #pragma unroll
    for (int n = 0; n < 4; ++n) {
      const int cg = col0 + wc*64 + n*16 + (lane&15);
      if (EPI == 2) {
        const int bq = cg >> 4, q = cg & 15;
        const int orig = (q>>2)*1024 + bq*4 + (q&3);   // permuted -> original col
        const float bb = bias1[orig] + bias2[orig];
        #pragma unroll
        for (int j = 0; j < 4; ++j) {
          const int row = rg0 + j;
          Cf[((size_t)bq*64 + (row>>5))*512 + (size_t)(row&31)*16 + q]
              = acc[m][n][j] + bb;
        }
      } else if (cg < Nreal) {
        float bb = 0.f;
        if (bias1) bb += bias1[cg];
        if (bias2) bb += bias2[cg];
        #pragma unroll
        for (int j = 0; j < 4; ++j) {
          float v = acc[m][n][j] + bb;
          if (EPI == 1) {
            v = tanhf(v * BN_SCALE);
            Cb[(size_t)(rg0+j)*Nreal + cg] = __float2bfloat16(v);
          } else {
            Cf[(size_t)(rg0+j)*Nreal + cg] = v;
          }
        }
      }
    }
  }
}

// ---------------------------------------------------------------------------
// Persistent LSTM recurrence. 256 blocks x 256 threads, 1 block/CU.
// Weights: LDS (96KB, staged once). h reads: normal cached loads (per-XCD L2
// as broadcast cache). h publish: 8B agent-scope relaxed stores (LLC).
// Flag publish: inline-asm global_store_dword sc0 sc1 (RELAXED — no
// buffer_wbl2; the release's full-L2 writeback was the per-step cost of
// rounds 4-7). Poll: inline-asm global_load_dword sc0 sc1 in a loop —
// asm volatile + memory clobbers make compiler reordering of the sync path
// impossible (the suspected cause of round 8's hang).
// Ordering without release: __syncthreads #2 drains vmcnt(0) in every wave
// (h-stores complete at LLC) BEFORE tid0's flag store; consumers touch each
// h line only after its flag and never earlier in the dispatch.
// ---------------------------------------------------------------------------
__global__ __launch_bounds__(256, 1)
void k_lstm_persist(const bf16* __restrict__ hinit, const float* __restrict__ cx,
                    const bf16* __restrict__ Wpack, const float* __restrict__ g0p,
                    const float* __restrict__ bih1, const float* __restrict__ bhh1,
                    bf16* __restrict__ h0_all, bf16* __restrict__ h1_all,
                    float* __restrict__ tail, unsigned* __restrict__ flags)
{
  const int b    = blockIdx.x;
  const int tid  = threadIdx.x;
  const int wave = tid >> 6, lane = tid & 63;

  __shared__ __align__(1024) bf16 Wlds[96*512];   // 96 KB: [chunk][lane][8]
  __shared__ float P[4][2][32][20];               // partial sums (padded)

  // one-time: stage this block's packed weights into LDS
  const bf16* wbase = Wpack + (size_t)b * 96 * 512;
  #pragma unroll
  for (int it = 0; it < 24; ++it) {
    const int chunk = it*4 + wave;                // wave-uniform
    gload16(wbase + (size_t)chunk*512 + lane*8,
            (void*)((char*)Wlds + (size_t)chunk*1024));
  }

  // gate/cell phase mapping: one LSTM cell per thread
  const int layer = tid >> 7;
  const int cell  = tid & 127;
  const int r     = cell >> 2;
  const int hc    = cell & 3;
  const int col   = b*4 + hc;
  float creg = cx[(size_t)layer*32768 + (size_t)r*1024 + col];
  float bsum[4];
  #pragma unroll
  for (int g = 0; g < 4; ++g)
    bsum[g] = (layer == 1) ? (bih1[g*1024 + col] + bhh1[g*1024 + col]) : 0.f;

  const int arow = lane & 15;
  const int koff = (lane >> 4) * 8;

  // per-lane poll pointers (wave 0 only uses them)
  const unsigned* fp0 = flags + (lane*4+0)*32;
  const unsigned* fp1 = flags + (lane*4+1)*32;
  const unsigned* fp2 = flags + (lane*4+2)*32;
  const unsigned* fp3 = flags + (lane*4+3)*32;

  __syncthreads();   // weights staged (drains vmcnt incl. global_load_lds)

  for (int s = 0; s < 65; ++s) {
    const bf16* hA = (s == 0) ? hinit           : h0_all + (size_t)(s-1)*32768;
    const bf16* hB = (s <= 1) ? (hinit + 32768) : h1_all + (size_t)(s-2)*32768;

    // normal cached h loads (L2 broadcast); all issued up front
    short8 a0[8], a1[8], c0[8], c1[8];
    #pragma unroll
    for (int i = 0; i < 8; ++i) {
      const int kb = wave*256 + i*32 + koff;
      a0[i] = *(const short8*)(hA + (size_t)arow*1024      + kb);
      a1[i] = *(const short8*)(hA + (size_t)(arow+16)*1024 + kb);
      c0[i] = *(const short8*)(hB + (size_t)arow*1024      + kb);
      c1[i] = *(const short8*)(hB + (size_t)(arow+16)*1024 + kb);
    }
    float gpre[4] = {0.f, 0.f, 0.f, 0.f};
    if (layer == 0 && s < 64) {
      const float* gr = g0p + ((size_t)(b*64 + s)*32 + r)*16;
      #pragma unroll
      for (int g = 0; g < 4; ++g) gpre[g] = gr[g*4 + hc];
    }

    f32x4 z = {0.f,0.f,0.f,0.f};
    f32x4 acc00 = z, acc01 = z, acc10 = z, acc11 = z;
    #pragma unroll
    for (int i = 0; i < 8; ++i) {
      const int ks = wave*8 + i;
      short8 w0 = *(const short8*)(Wlds + ((size_t)(     ks)*64 + lane)*8);
      short8 w1 = *(const short8*)(Wlds + ((size_t)(32 + ks)*64 + lane)*8);
      short8 w2 = *(const short8*)(Wlds + ((size_t)(64 + ks)*64 + lane)*8);
      acc00 = MFMA_BF16(a0[i], w0, acc00);   // layer0: Whh0 @ h0[s-1]
      acc01 = MFMA_BF16(a1[i], w0, acc01);
      acc10 = MFMA_BF16(a0[i], w1, acc10);   // layer1: Wih1 @ h0[s-1]
      acc11 = MFMA_BF16(a1[i], w1, acc11);
      acc10 = MFMA_BF16(c0[i], w2, acc10);   // layer1 += Whh1 @ h1[s-2]
      acc11 = MFMA_BF16(c1[i], w2, acc11);
    }

    #pragma unroll
    for (int j = 0; j < 4; ++j) {
      const int pr = (lane >> 4)*4 + j;
      P[wave][0][pr     ][lane & 15] = acc00[j];
      P[wave][0][pr + 16][lane & 15] = acc01[j];
      P[wave][1][pr     ][lane & 15] = acc10[j];
      P[wave][1][pr + 16][lane & 15] = acc11[j];
    }
    __syncthreads();                         // #1: P complete

    const int t = s - layer;
    if (t >= 0 && t < 64) {
      float v[4];
      #pragma unroll
      for (int g = 0; g < 4; ++g) {
        const int j = g*4 + hc;
        v[g] = P[0][layer][r][j] + P[1][layer][r][j]
             + P[2][layer][r][j] + P[3][layer][r][j] + bsum[g] + gpre[g];
      }
      const float iv = 1.f/(1.f + expf(-v[0]));
      const float fv = 1.f/(1.f + expf(-v[1]));
      const float gv = tanhf(v[2]);
      const float ov = 1.f/(1.f + expf(-v[3]));
      creg = fv*creg + iv*gv;
      const float hn = ov*tanhf(creg);
      // gather 4 cells -> one 8B agent-relaxed store straight to LLC
      unsigned hu  = bf16bits(hn);
      unsigned p01 = hu | ((unsigned)__shfl_xor((int)hu, 1) << 16);
      unsigned p23 = (unsigned)__shfl_xor((int)p01, 2);
      if (hc == 0) {
        bf16* hp = (layer ? h1_all : h0_all) + (size_t)t*32768 + (size_t)r*1024 + b*4;
        unsigned long long v64 = (unsigned long long)p01
                               | ((unsigned long long)p23 << 32);
        __hip_atomic_store((unsigned long long*)hp, v64,
                           __ATOMIC_RELAXED, __HIP_MEMORY_SCOPE_AGENT);
      }
      if (t == 63) {
        tail[(size_t)layer*32768 + (size_t)r*1024 + col]         = hn;
        tail[65536 + (size_t)layer*32768 + (size_t)r*1024 + col] = creg;
      }
    }
    if (s == 64) break;

    __syncthreads();                         // #2: drain h publishes (vmcnt 0)
    if (tid == 0) {
      // RELAXED publish straight to LLC (sc1), pinned by asm volatile:
      // no buffer_wbl2, no compiler reordering.
      asm volatile("global_store_dword %0, %1, off sc0 sc1\n\t"
                   "s_waitcnt vmcnt(0)"
                   :: "v"(flags + b*32), "v"((unsigned)(s + 1)) : "memory");
    }
    if (wave == 0) {                         // only wave 0 polls
      const unsigned su = (unsigned)s;
      for (;;) {
        unsigned v0, v1, v2, v3;
        asm volatile("global_load_dword %0, %1, off sc0 sc1" : "=v"(v0) : "v"(fp0));
        asm volatile("global_load_dword %0, %1, off sc0 sc1" : "=v"(v1) : "v"(fp1));
        asm volatile("global_load_dword %0, %1, off sc0 sc1" : "=v"(v2) : "v"(fp2));
        asm volatile("global_load_dword %0, %1, off sc0 sc1" : "=v"(v3) : "v"(fp3));
        asm volatile("s_waitcnt vmcnt(0)" ::: "memory");
        bool ok = (v0 > su) & (v1 > su) & (v2 > su) & (v3 > su);
        if (__all(ok)) break;
        __builtin_amdgcn_s_sleep(1);
      }
    }
    __syncthreads();                         // #3: release all waves
    asm volatile("" ::: "memory");           // no hoisting of h loads above
    __builtin_amdgcn_sched_barrier(0);
  }
}

// ---------------------------------------------------------------------------
// Pack Whh0 / Wih1 / Whh1 into per-block MFMA-fragment order (bf16).
// ---------------------------------------------------------------------------
__global__ __launch_bounds__(256)
void k_pack(const float* __restrict__ Whh0, const float* __restrict__ Wih1,
            const float* __restrict__ Whh1, bf16* __restrict__ Wpack)
{
  const int b = blockIdx.x;
  #pragma unroll 4
  for (int it = 0; it < 24; ++it) {
    const int idx = it*256 + threadIdx.x;
    const int chunkp = idx >> 6;            // 0..95
    const int l = idx & 63;
    const int p = chunkp >> 5, c = chunkp & 31;
    const float* W = (p == 0) ? Whh0 : (p == 1 ? Wih1 : Whh1);
    const int j = l & 15;
    const int row = (j>>2)*1024 + b*4 + (j&3);
    const int k = c*32 + (l>>4)*8;
    const float* src = W + (size_t)row*1024 + k;
    bf16* dst = Wpack + ((size_t)(b*96 + chunkp)*64 + l)*8;
    #pragma unroll
    for (int q = 0; q < 8; ++q) dst[q] = __float2bfloat16(src[q]);
  }
}

// ---------------------------------------------------------------------------
// small helpers
// ---------------------------------------------------------------------------
__global__ void k_cvt(const float* __restrict__ s, bf16* __restrict__ d, long n) {
  long i = (long)blockIdx.x*blockDim.x + threadIdx.x;
  if (i < n) d[i] = __float2bfloat16(s[i]);
}

// Wih0 cast with ROW PERMUTATION: dst row n <- src row ((n>>2)&3)*1024 + (n>>4)*4 + (n&3)
__global__ void k_cvt_perm(const float* __restrict__ src, bf16* __restrict__ dst) {
  const int n = blockIdx.x;                 // 0..4095 (permuted row)
  const int orig = ((n>>2)&3)*1024 + (n>>4)*4 + (n&3);
  const float4 v = ((const float4*)(src + (size_t)orig*512))[threadIdx.x];
  bf16* d = dst + (size_t)n*512 + threadIdx.x*4;
  d[0] = __float2bfloat16(v.x); d[1] = __float2bfloat16(v.y);
  d[2] = __float2bfloat16(v.z); d[3] = __float2bfloat16(v.w);
}

__global__ void k_cvt_pad(const float* __restrict__ s, bf16* __restrict__ d,
                          long n, long nrows_real, int rowlen) {
  long i = (long)blockIdx.x*blockDim.x + threadIdx.x;
  if (i < n) {
    long r = i / rowlen;
    d[i] = (r < nrows_real) ? __float2bfloat16(s[i]) : __float2bfloat16(0.f);
  }
}

__global__ void k_init(const float* __restrict__ hx, bf16* __restrict__ hinit,
                       unsigned* __restrict__ flags) {
  int i = blockIdx.x*blockDim.x + threadIdx.x;
  if (i < 8192) flags[i] = 0u;
  if (i < 65536) hinit[i] = __float2bfloat16(hx[i]);
}

__global__ void k_embed(const int* __restrict__ ids, const float* __restrict__ emb_w,
                        bf16* __restrict__ out) {
  const int row = blockIdx.x;
  const int tok = ids[row];
  const float4 v = ((const float4*)(emb_w + (size_t)tok*512))[threadIdx.x];
  bf16* d = out + (size_t)row*512 + threadIdx.x*4;
  d[0] = __float2bfloat16(v.x); d[1] = __float2bfloat16(v.y);
  d[2] = __float2bfloat16(v.z); d[3] = __float2bfloat16(v.w);
}

// ---------------------------------------------------------------------------
extern "C" void kernel_launch(void* const* d_in, const int* in_sizes, int n_in,
                              void* d_out, int out_size, void* d_ws, size_t ws_size,
                              hipStream_t stream) {
  const int*   ids  = (const int*)d_in[0];
  const float* hx   = (const float*)d_in[1];
  const float* cx   = (const float*)d_in[2];
  const float* embw = (const float*)d_in[3];
  const float* Wih0 = (const float*)d_in[4];
  const float* Whh0 = (const float*)d_in[5];
  const float* bih0 = (const float*)d_in[6];
  const float* bhh0 = (const float*)d_in[7];
  const float* Wih1 = (const float*)d_in[8];
  const float* Whh1 = (const float*)d_in[9];
  const float* bih1 = (const float*)d_in[10];
  const float* bhh1 = (const float*)d_in[11];
  const float* Wp   = (const float*)d_in[12];
  const float* bp   = (const float*)d_in[13];
  const float* Wd   = (const float*)d_in[14];
  const float* bd   = (const float*)d_in[15];
  float* out = (float*)d_out;

  char* w = (char*)d_ws;
  bf16* Wih0b = (bf16*)w; w += 4096l*512*2;       // permuted rows
  bf16* Wpack = (bf16*)w; w += 256l*96*64*8*2;    // 24 MB packed recurrent weights
  bf16* Wpb   = (bf16*)w; w += 512l*1024*2;
  bf16* Wdb   = (bf16*)w; w += 50048l*512*2;
  bf16* embb  = (bf16*)w; w += 2048l*512*2;
  float* g0p  = (float*)w; w += 2048l*4096*4;     // [b][t][r][q] layout
  bf16* h0a   = (bf16*)w; w += 2048l*1024*2;
  bf16* h1a   = (bf16*)w; w += 2048l*1024*2;
  bf16* hinit = (bf16*)w; w += 2l*32*1024*2;
  bf16* pb    = (bf16*)w; w += 2048l*512*2;
  unsigned* flags = (unsigned*)w; w += 8192*4;

  k_cvt_perm<<<4096, 128, 0, stream>>>(Wih0, Wih0b);
  k_cvt<<<(512l*1024 + 255)/256, 256, 0, stream>>>(Wp, Wpb, 512l*1024);
  k_cvt_pad<<<(50048l*512 + 255)/256, 256, 0, stream>>>(Wd, Wdb, 50048l*512, 50000, 512);
  k_init<<<256, 256, 0, stream>>>(hx, hinit, flags);
  k_embed<<<2048, 128, 0, stream>>>(ids, embw, embb);
  k_pack<<<256, 256, 0, stream>>>(Whh0, Wih1, Whh1, Wpack);

  // layer-0 input-side GEMM for ALL timesteps -> g0p layout; folds bih0+bhh0
  gemm_bt<2><<<dim3(32, 16), 256, 0, stream>>>(
      embb, Wih0b, bih0, bhh0, g0p, nullptr, 2048, 4096, 512, 4096);

  // persistent pipelined recurrence: one dispatch, 65 super-steps
  float* tail = out + 102400000l;
  k_lstm_persist<<<256, 256, 0, stream>>>(hinit, cx, Wpack, g0p, bih1, bhh1,
                                          h0a, h1a, tail, flags);

  // predictor: Linear + BN(eval) + tanh -> bf16
  gemm_bt<1><<<dim3(4, 16), 256, 0, stream>>>(
      h1a, Wpb, bp, nullptr, nullptr, pb, 2048, 512, 1024, 512);

  // decoder: [2048,512] @ [50048,512]^T (padded), guarded store to 50000
  gemm_bt<0><<<dim3(391, 16), 256, 0, stream>>>(
      pb, Wdb, bd, nullptr, out, nullptr, 2048, 50048, 512, 50000);
}